// Round 3
// baseline (175.365 us; speedup 1.0000x reference)
//
#include <hip/hip_runtime.h>
#include <hip/hip_bf16.h>
#include <stdint.h>

// QuantizedLinearFSDP: out[m][n] = sum_k x[m][k] * W[n][k] + bias[n]
//   W[n][g*128+s] = codebooks[n][g][codes[n][g][s]]
// M=2048, N=4096, K=4096, G=32, S=128, B=16.
//
// R8: 3-stage prefetch pipeline. R7 (2-stage, 1 block/CU) exposed ~2000 cy
// of L2 transfer+latency per phase: stage loads got only one phase (~1200cy)
// to land, and the vmcnt(12->6) wait ate 65% of each phase (MfmaUtil 27%).
// Now 3 LDS buffers (48KB/stage x 3 = 144KB <= 160KB): prefetch distance 2
// phases (~2400cy) covers L2 transfer (~860cy) + latency (~450cy) with slack.
// Steady-state wait is vmcnt(12) = 2 stages in flight; tail 6 -> 0.
// Datapath (compute tile, XOR swizzle, staging addrs, k-pair reduction,
// epilogue) is byte-identical to R7's verified version -> same output bits.
// Prepass unchanged from R5 (verified).

#define M_DIM 2048
#define N_DIM 4096
#define K_DIM 4096

typedef __attribute__((ext_vector_type(4))) int i32x4;

__device__ __forceinline__ void async_load16(const void* g, void* l) {
    __builtin_amdgcn_global_load_lds(
        (const __attribute__((address_space(1))) uint32_t*)(uintptr_t)g,
        (__attribute__((address_space(3))) uint32_t*)(uint32_t)(uintptr_t)l,
        16, 0, 0);
}

__device__ __forceinline__ uint32_t pack4(int a, int b, int c, int d) {
    return (uint32_t)(a & 255) | ((uint32_t)(b & 255) << 8) |
           ((uint32_t)(c & 255) << 16) | ((uint32_t)(d & 255) << 24);
}

__device__ __forceinline__ int q8(float v, float inv) {
    return (int)rintf(v * inv);   // RNE, |v*inv| <= 127 by construction
}

// ---------------- pre-pass: quantize W and x to i8 + per-row scales -------
// blocks [0, 4096): W row o. Stage 512 cb floats in LDS, absmax -> scale,
//   quantize 4096 codes (16/thread) to i8, write as dwords.
// blocks [4096, 6144): x row m. absmax over 4096 floats -> scale, quantize.
__global__ __launch_bounds__(256) void prepass_q8(
    const float* __restrict__ cb,      // [4096][32][16]
    const int* __restrict__ codes,     // [4096][32][128]
    const float* __restrict__ x,       // [2048][4096]
    uint32_t* __restrict__ wq,         // [4096][1024] dwords (i8x4)
    uint32_t* __restrict__ xq,         // [2048][1024] dwords (i8x4)
    float* __restrict__ sw,            // [4096]
    float* __restrict__ sx)            // [2048]
{
    __shared__ float scb[512];
    __shared__ float red[256];
    const int b = blockIdx.x, t = threadIdx.x;
    if (b < N_DIM) {
        const int o = b;
        const float c0 = cb[(size_t)o * 512 + t];
        const float c1 = cb[(size_t)o * 512 + 256 + t];
        scb[t] = c0; scb[t + 256] = c1;
        red[t] = fmaxf(fabsf(c0), fabsf(c1));
        __syncthreads();
        for (int s = 128; s > 0; s >>= 1) {
            if (t < s) red[t] = fmaxf(red[t], red[t + s]);
            __syncthreads();
        }
        const float amax = fmaxf(red[0], 1e-20f);
        const float inv = 127.0f / amax;
        if (t == 0) sw[o] = amax / 127.0f;
        const int* crow = codes + (size_t)o * K_DIM;
        uint32_t* orow = wq + (size_t)o * 1024;
#pragma unroll
        for (int i = 0; i < 4; ++i) {
            const int d = t + i * 256;                 // dword index 0..1023
            const int4 c = *(const int4*)(crow + d * 4);
            const float* g = scb + (d >> 5) * 16;      // group = (4d)>>7
            orow[d] = pack4(q8(g[c.x], inv), q8(g[c.y], inv),
                            q8(g[c.z], inv), q8(g[c.w], inv));
        }
    } else {
        const int m = b - N_DIM;
        const float* row = x + (size_t)m * K_DIM;
        float4 v[4];
        float am = 0.f;
#pragma unroll
        for (int i = 0; i < 4; ++i) {
            v[i] = *(const float4*)(row + (size_t)(t + i * 256) * 4);
            am = fmaxf(am, fmaxf(fmaxf(fabsf(v[i].x), fabsf(v[i].y)),
                                 fmaxf(fabsf(v[i].z), fabsf(v[i].w))));
        }
        red[t] = am;
        __syncthreads();
        for (int s = 128; s > 0; s >>= 1) {
            if (t < s) red[t] = fmaxf(red[t], red[t + s]);
            __syncthreads();
        }
        const float amax = fmaxf(red[0], 1e-20f);
        const float inv = 127.0f / amax;
        if (t == 0) sx[m] = amax / 127.0f;
        uint32_t* orow = xq + (size_t)m * 1024;
#pragma unroll
        for (int i = 0; i < 4; ++i)
            orow[t + i * 256] = pack4(q8(v[i].x, inv), q8(v[i].y, inv),
                                      q8(v[i].z, inv), q8(v[i].w, inv));
    }
}

// ---------------- main GEMM (i8): C = A*B^T scaled + bias ----------------
// A [2048][4096] i8, B [4096][4096] i8, C f32. BM=256 x BN=128 tile,
// BK=128, 512 threads = 8 waves: wk=w>>2 (k-half), wm=((w>>1)&1)*128,
// wn=(w&1)*64. Each wave: RM=8 x RN=4 of 16x16x64 frags = 128x64 output
// over its 64-k half; k-pair LDS reduction at the end (verified R5).
// LDS: 3-stage As [256][128] (32KB) + Bs [128][128] (16KB) = 48KB/stage.
// Row = 128B = 8 x 16B chunks; slot s of row r holds global k-chunk
// s ^ (r&7) -> 2-way banks only (0 conflicts verified on this swizzle).

__device__ __forceinline__ void compute_tile(
    const unsigned char* As, const unsigned char* Bs,
    const int wm, const int wn, const int l15, const int fs,
    i32x4 acc[8][4])
{
    i32x4 af[8], bf[4];
#pragma unroll
    for (int i = 0; i < 8; ++i)
        af[i] = *(const i32x4*)(As + (wm + i * 16 + l15) * 128 + fs);
#pragma unroll
    for (int i = 0; i < 4; ++i)
        bf[i] = *(const i32x4*)(Bs + (wn + i * 16 + l15) * 128 + fs);
#pragma unroll
    for (int mi = 0; mi < 8; ++mi)
#pragma unroll
        for (int ni = 0; ni < 4; ++ni)
            acc[mi][ni] = __builtin_amdgcn_mfma_i32_16x16x64_i8(
                af[mi], bf[ni], acc[mi][ni], 0, 0, 0);
}

__global__ __launch_bounds__(512, 2) void gemm_i8(
    const unsigned char* __restrict__ A,
    const unsigned char* __restrict__ B,
    const float* __restrict__ sx,
    const float* __restrict__ sw,
    const float* __restrict__ bias,
    float* __restrict__ C)
{
    __shared__ __align__(16) unsigned char smem[147456];
    unsigned char* As0 = smem;               // stage 0: A 32KB + B 16KB
    unsigned char* Bs0 = smem + 32768;
    unsigned char* As1 = smem + 49152;       // stage 1
    unsigned char* Bs1 = smem + 81920;
    unsigned char* As2 = smem + 98304;       // stage 2
    unsigned char* Bs2 = smem + 131072;

    const int tid  = threadIdx.x;
    const int w    = tid >> 6;        // wave 0..7
    const int lane = tid & 63;
    const int l15  = lane & 15;
    const int quad = lane >> 4;
    const int m0   = blockIdx.y * 256;
    const int n0   = blockIdx.x * 128;
    const int wk   = w >> 2;          // k-half 0/1
    const int wm   = ((w >> 1) & 1) * 128;
    const int wn   = (w & 1) * 64;

    // staging: per call, wave w / lane l covers row (w*8 + l>>3) of a
    // 64-row group, slot l&7 holding global k-chunk (l&7)^(l>>3)
    // (row&7 == l>>3 since w*8 and the 64-row group offsets are ===0 mod 8).
    const int r8 = lane >> 3;                        // 0..7
    const int sc = (lane & 7) ^ r8;                  // global k-chunk
    const unsigned char* gA = A + (size_t)(m0 + w * 8 + r8) * K_DIM + sc * 16;
    const unsigned char* gB = B + (size_t)(n0 + w * 8 + r8) * K_DIM + sc * 16;

    // frag reads: row = wm/wn + i*16 + l15 -> row&7 == l15&7. Wave's wanted
    // chunk = wk*4 + quad -> slot = chunk ^ (l15&7). Byte offset in row:
    const int fs = (((wk << 2) + quad) ^ (l15 & 7)) * 16;

    auto stage = [&](unsigned char* As, unsigned char* Bs, int k) {
        // A: 256 rows = 4 x 64-row groups; B: 128 rows = 2 groups.
        async_load16(gA + k,                        As +         w * 1024);
        async_load16(gA + k + (size_t)64  * K_DIM,  As + 8192  + w * 1024);
        async_load16(gA + k + (size_t)128 * K_DIM,  As + 16384 + w * 1024);
        async_load16(gA + k + (size_t)192 * K_DIM,  As + 24576 + w * 1024);
        async_load16(gB + k,                        Bs +         w * 1024);
        async_load16(gB + k + (size_t)64  * K_DIM,  Bs + 8192  + w * 1024);
    };

    i32x4 acc[8][4] = {};

    // Prologue: tiles 0,1 in flight.
    stage(As0, Bs0, 0);
    stage(As1, Bs1, 128);

    // Main loop: 30 tiles (10 x unroll-3), each phase prefetches tile t+2
    // and computes tile t with vmcnt(12) = 2 stages (12 loads) in flight.
#define PHASE(AsC, BsC, AsP, BsP, kpre, vm)                         \
    do {                                                            \
        stage(AsP, BsP, (kpre));                                    \
        asm volatile("s_waitcnt vmcnt(" #vm ")" ::: "memory");      \
        __builtin_amdgcn_s_barrier();                               \
        asm volatile("" ::: "memory");                              \
        compute_tile(AsC, BsC, wm, wn, l15, fs, acc);               \
        asm volatile("s_waitcnt lgkmcnt(0)" ::: "memory");          \
        __builtin_amdgcn_sched_barrier(0);                          \
        __builtin_amdgcn_s_barrier();                               \
    } while (0)

    for (int it = 0; it < 10; ++it) {
        const int t = it * 3;
        PHASE(As0, Bs0, As2, Bs2, (t + 2) * 128, 12);   // compute t
        PHASE(As1, Bs1, As0, Bs0, (t + 3) * 128, 12);   // compute t+1
        PHASE(As2, Bs2, As1, Bs1, (t + 4) * 128, 12);   // compute t+2
    }
#undef PHASE

    // Tail: tiles 30 (stage0) and 31 (stage1), all loads already issued.
    asm volatile("s_waitcnt vmcnt(6)" ::: "memory");    // tile 30 landed
    __builtin_amdgcn_s_barrier();
    asm volatile("" ::: "memory");
    compute_tile(As0, Bs0, wm, wn, l15, fs, acc);
    asm volatile("s_waitcnt lgkmcnt(0)" ::: "memory");
    __builtin_amdgcn_sched_barrier(0);
    __builtin_amdgcn_s_barrier();

    asm volatile("s_waitcnt vmcnt(0)" ::: "memory");    // tile 31 landed
    __builtin_amdgcn_s_barrier();
    asm volatile("" ::: "memory");
    compute_tile(As1, Bs1, wm, wn, l15, fs, acc);
    asm volatile("s_waitcnt lgkmcnt(0)" ::: "memory");
    __builtin_amdgcn_sched_barrier(0);
    __builtin_amdgcn_s_barrier();   // all LDS reads done -> smem reusable

    // ---- k-pair reduction: wave w (wk=0) += wave w+4 (wk=1), via LDS ----
    // Layout: vec slot (mi*4+ni)*64 + lane -> lane's i32x4 contiguous
    // (b128 writes/reads, fully sequential per wave -> conflict-free).
    // 2 waves at a time: 2 x 32 KB = 64 KB <= smem.
    i32x4* red = (i32x4*)smem;
    if (w == 4 || w == 5) {
        i32x4* dst = red + (w & 1) * 2048;
#pragma unroll
        for (int mi = 0; mi < 8; ++mi)
#pragma unroll
            for (int ni = 0; ni < 4; ++ni)
                dst[(mi * 4 + ni) * 64 + lane] = acc[mi][ni];
    }
    __syncthreads();
    if (w == 0 || w == 1) {
        const i32x4* src = red + (w & 1) * 2048;
#pragma unroll
        for (int mi = 0; mi < 8; ++mi)
#pragma unroll
            for (int ni = 0; ni < 4; ++ni) {
                const i32x4 v = src[(mi * 4 + ni) * 64 + lane];
                acc[mi][ni] = acc[mi][ni] + v;
            }
    }
    __syncthreads();
    if (w == 6 || w == 7) {
        i32x4* dst = red + (w & 1) * 2048;
#pragma unroll
        for (int mi = 0; mi < 8; ++mi)
#pragma unroll
            for (int ni = 0; ni < 4; ++ni)
                dst[(mi * 4 + ni) * 64 + lane] = acc[mi][ni];
    }
    __syncthreads();
    if (w == 2 || w == 3) {
        const i32x4* src = red + (w & 1) * 2048;
#pragma unroll
        for (int mi = 0; mi < 8; ++mi)
#pragma unroll
            for (int ni = 0; ni < 4; ++ni) {
                const i32x4 v = src[(mi * 4 + ni) * 64 + lane];
                acc[mi][ni] = acc[mi][ni] + v;
            }
    }

    // ---- epilogue (waves 0..3): C/D col = lane&15, row = quad*4+reg ----
    if (w < 4) {
        float swv[4], bv[4];
#pragma unroll
        for (int ni = 0; ni < 4; ++ni) {
            const int col = n0 + wn + ni * 16 + l15;
            swv[ni] = sw[col];
            bv[ni]  = bias[col];
        }
#pragma unroll
        for (int mi = 0; mi < 8; ++mi) {
            float sxr[4];
#pragma unroll
            for (int r = 0; r < 4; ++r)
                sxr[r] = sx[m0 + wm + mi * 16 + quad * 4 + r];
#pragma unroll
            for (int ni = 0; ni < 4; ++ni) {
                const int col = n0 + wn + ni * 16 + l15;
                float* cp = C + (size_t)(m0 + wm + mi * 16 + quad * 4) * N_DIM + col;
#pragma unroll
                for (int r = 0; r < 4; ++r)
                    cp[(size_t)r * N_DIM] =
                        (float)acc[mi][ni][r] * (sxr[r] * swv[ni]) + bv[ni];
            }
        }
    }
}

// ---------------- fallback (ws too small): naive fp32 ----------------
__global__ __launch_bounds__(256) void naive_kernel(
    const float* __restrict__ x, const float* __restrict__ cb,
    const int* __restrict__ codes, const float* __restrict__ bias,
    float* __restrict__ out)
{
    const size_t idx = (size_t)blockIdx.x * 256 + threadIdx.x;  // m*4096 + n
    const int n = (int)(idx & 4095);
    const int m = (int)(idx >> 12);
    const float* xr = x + (size_t)m * K_DIM;
    float s = bias[n];
    for (int g = 0; g < 32; ++g) {
        const float* cbr = cb + ((size_t)n * 32 + g) * 16;
        const int* cr = codes + ((size_t)n * 32 + g) * 128;
        const float* xg = xr + g * 128;
        for (int ss = 0; ss < 128; ++ss) s += xg[ss] * cbr[cr[ss]];
    }
    out[idx] = s;
}

extern "C" void kernel_launch(void* const* d_in, const int* in_sizes, int n_in,
                              void* d_out, int out_size, void* d_ws, size_t ws_size,
                              hipStream_t stream) {
    const float* x     = (const float*)d_in[0];   // [2,1024,4096] f32
    const float* cb    = (const float*)d_in[1];   // [4096,32,16]  f32
    const int*   codes = (const int*)d_in[2];     // [4096,32,128] i32
    const float* bias  = (const float*)d_in[3];   // [4096]        f32
    float* out = (float*)d_out;                   // [2,1024,4096] f32

    const size_t szW = (size_t)N_DIM * K_DIM;          // 16.78 MB i8
    const size_t szX = (size_t)M_DIM * K_DIM;          // 8.39 MB i8
    const size_t need = szW + szX + (N_DIM + M_DIM) * sizeof(float);

    if (ws_size >= need) {
        unsigned char* Wq = (unsigned char*)d_ws;
        unsigned char* Xq = Wq + szW;
        float* sw = (float*)(Xq + szX);
        float* sx = sw + N_DIM;
        prepass_q8<<<dim3(N_DIM + M_DIM), dim3(256), 0, stream>>>(
            cb, codes, x, (uint32_t*)Wq, (uint32_t*)Xq, sw, sx);
        gemm_i8<<<dim3(N_DIM / 128, M_DIM / 256), dim3(512), 0, stream>>>(
            Xq, Wq, sx, sw, bias, out);
    } else {
        naive_kernel<<<dim3((M_DIM * N_DIM) / 256), dim3(256), 0, stream>>>(x, cb, codes, bias, out);
    }
}

// Round 4
// 170.485 us; speedup vs baseline: 1.0286x; 1.0286x over previous
//
#include <hip/hip_runtime.h>
#include <hip/hip_bf16.h>
#include <stdint.h>

// QuantizedLinearFSDP: out[m][n] = sum_k x[m][k] * W[n][k] + bias[n]
//   W[n][g*128+s] = codebooks[n][g][codes[n][g][s]]
// M=2048, N=4096, K=4096, G=32, S=128, B=16.
//
// R9: 8-phase-style fine interleave (docs T3+T4+T5). R7/R8's coarse
// stage-burst + lockstep compute serialized the VMEM/LDS/MFMA pipes
// (m196's documented failure). Now each K-tile = 2 phases of
// {ds_read 8|4 x b128 ; stage ONE unit (A or B of tile t+2) ; barrier ;
//  setprio(1) 16 MFMA setprio(0) ; barrier}, 3 LDS stages (48KB x 3),
// one counted s_waitcnt vmcnt(6) per K-tile (never 0 in main loop):
// at tile-t end outstanding = t+1,t+2 = 12 loads; vmcnt(6) retires
// exactly tile t+1. Last-staged unit gets ~2 phases of flight.
// Geometry unchanged from R7 (verified): BM=256 BN=128 BK=128, 8 waves
// 2M x 2N x 2K, wave owns 128x64 over its 64-k half (RM=8, RN=4),
// XOR chunk swizzle (0 conflicts), k-pair LDS reduction, same epilogue.
// i8 math identical -> bit-identical output. Prepass unchanged from R5.

#define M_DIM 2048
#define N_DIM 4096
#define K_DIM 4096

typedef __attribute__((ext_vector_type(4))) int i32x4;

__device__ __forceinline__ void async_load16(const void* g, void* l) {
    __builtin_amdgcn_global_load_lds(
        (const __attribute__((address_space(1))) uint32_t*)(uintptr_t)g,
        (__attribute__((address_space(3))) uint32_t*)(uint32_t)(uintptr_t)l,
        16, 0, 0);
}

__device__ __forceinline__ uint32_t pack4(int a, int b, int c, int d) {
    return (uint32_t)(a & 255) | ((uint32_t)(b & 255) << 8) |
           ((uint32_t)(c & 255) << 16) | ((uint32_t)(d & 255) << 24);
}

__device__ __forceinline__ int q8(float v, float inv) {
    return (int)rintf(v * inv);   // RNE, |v*inv| <= 127 by construction
}

// ---------------- pre-pass: quantize W and x to i8 + per-row scales -------
__global__ __launch_bounds__(256) void prepass_q8(
    const float* __restrict__ cb,      // [4096][32][16]
    const int* __restrict__ codes,     // [4096][32][128]
    const float* __restrict__ x,       // [2048][4096]
    uint32_t* __restrict__ wq,         // [4096][1024] dwords (i8x4)
    uint32_t* __restrict__ xq,         // [2048][1024] dwords (i8x4)
    float* __restrict__ sw,            // [4096]
    float* __restrict__ sx)            // [2048]
{
    __shared__ float scb[512];
    __shared__ float red[256];
    const int b = blockIdx.x, t = threadIdx.x;
    if (b < N_DIM) {
        const int o = b;
        const float c0 = cb[(size_t)o * 512 + t];
        const float c1 = cb[(size_t)o * 512 + 256 + t];
        scb[t] = c0; scb[t + 256] = c1;
        red[t] = fmaxf(fabsf(c0), fabsf(c1));
        __syncthreads();
        for (int s = 128; s > 0; s >>= 1) {
            if (t < s) red[t] = fmaxf(red[t], red[t + s]);
            __syncthreads();
        }
        const float amax = fmaxf(red[0], 1e-20f);
        const float inv = 127.0f / amax;
        if (t == 0) sw[o] = amax / 127.0f;
        const int* crow = codes + (size_t)o * K_DIM;
        uint32_t* orow = wq + (size_t)o * 1024;
#pragma unroll
        for (int i = 0; i < 4; ++i) {
            const int d = t + i * 256;                 // dword index 0..1023
            const int4 c = *(const int4*)(crow + d * 4);
            const float* g = scb + (d >> 5) * 16;      // group = (4d)>>7
            orow[d] = pack4(q8(g[c.x], inv), q8(g[c.y], inv),
                            q8(g[c.z], inv), q8(g[c.w], inv));
        }
    } else {
        const int m = b - N_DIM;
        const float* row = x + (size_t)m * K_DIM;
        float4 v[4];
        float am = 0.f;
#pragma unroll
        for (int i = 0; i < 4; ++i) {
            v[i] = *(const float4*)(row + (size_t)(t + i * 256) * 4);
            am = fmaxf(am, fmaxf(fmaxf(fabsf(v[i].x), fabsf(v[i].y)),
                                 fmaxf(fabsf(v[i].z), fabsf(v[i].w))));
        }
        red[t] = am;
        __syncthreads();
        for (int s = 128; s > 0; s >>= 1) {
            if (t < s) red[t] = fmaxf(red[t], red[t + s]);
            __syncthreads();
        }
        const float amax = fmaxf(red[0], 1e-20f);
        const float inv = 127.0f / amax;
        if (t == 0) sx[m] = amax / 127.0f;
        uint32_t* orow = xq + (size_t)m * 1024;
#pragma unroll
        for (int i = 0; i < 4; ++i)
            orow[t + i * 256] = pack4(q8(v[i].x, inv), q8(v[i].y, inv),
                                      q8(v[i].z, inv), q8(v[i].w, inv));
    }
}

// ---------------- main GEMM (i8): C = A*B^T scaled + bias ----------------
// A [2048][4096] i8, B [4096][4096] i8, C f32. BM=256 x BN=128, BK=128,
// 512 threads = 8 waves: wk=w>>2 (k-half), wm=((w>>1)&1)*128, wn=(w&1)*64.
// LDS: 3 stages x (As [256][128] 32KB + Bs [128][128] 16KB) = 144KB.
// Row = 128B = 8 x 16B chunks; slot s of row r holds global k-chunk
// s ^ (r&7) -> 2-way banks only (0 conflicts verified).

// VM: 6 = steady (retire tile t+1, keep t+2 in flight), 0 = pre-last-tile
// drain, -1 = none (last tile).
template <bool STAGE, int VM>
__device__ __forceinline__ void ktile(
    const unsigned char* As_c, const unsigned char* Bs_c,
    unsigned char* As_p, unsigned char* Bs_p, int kpre,
    const unsigned char* gA, const unsigned char* gB,
    int wm, int wn, int l15, int fs, int w, i32x4 acc[8][4])
{
    i32x4 af[4], bf[4];
    // ---- phase 1: q0 reads + stage A(t+2) + 16 MFMA (acc rows 0..3) ----
#pragma unroll
    for (int i = 0; i < 4; ++i)
        af[i] = *(const i32x4*)(As_c + (wm + i * 16 + l15) * 128 + fs);
#pragma unroll
    for (int i = 0; i < 4; ++i)
        bf[i] = *(const i32x4*)(Bs_c + (wn + i * 16 + l15) * 128 + fs);
    if (STAGE) {
        async_load16(gA + kpre,                         As_p +         w * 1024);
        async_load16(gA + kpre + (size_t)64  * K_DIM,   As_p + 8192  + w * 1024);
        async_load16(gA + kpre + (size_t)128 * K_DIM,   As_p + 16384 + w * 1024);
        async_load16(gA + kpre + (size_t)192 * K_DIM,   As_p + 24576 + w * 1024);
    }
    asm volatile("" ::: "memory");
    __builtin_amdgcn_s_barrier();
    __builtin_amdgcn_s_setprio(1);
#pragma unroll
    for (int mi = 0; mi < 4; ++mi)
#pragma unroll
        for (int ni = 0; ni < 4; ++ni)
            acc[mi][ni] = __builtin_amdgcn_mfma_i32_16x16x64_i8(
                af[mi], bf[ni], acc[mi][ni], 0, 0, 0);
    __builtin_amdgcn_s_setprio(0);
    asm volatile("" ::: "memory");
    __builtin_amdgcn_s_barrier();

    // ---- phase 2: q1 reads + stage B(t+2) + 16 MFMA (acc rows 4..7) ----
#pragma unroll
    for (int i = 0; i < 4; ++i)
        af[i] = *(const i32x4*)(As_c + (wm + 64 + i * 16 + l15) * 128 + fs);
    if (STAGE) {
        async_load16(gB + kpre,                         Bs_p +        w * 1024);
        async_load16(gB + kpre + (size_t)64 * K_DIM,    Bs_p + 8192 + w * 1024);
    }
    asm volatile("" ::: "memory");
    __builtin_amdgcn_s_barrier();
    __builtin_amdgcn_s_setprio(1);
#pragma unroll
    for (int mi = 0; mi < 4; ++mi)
#pragma unroll
        for (int ni = 0; ni < 4; ++ni)
            acc[4 + mi][ni] = __builtin_amdgcn_mfma_i32_16x16x64_i8(
                af[mi], bf[ni], acc[4 + mi][ni], 0, 0, 0);
    __builtin_amdgcn_s_setprio(0);
    if (VM == 6)      asm volatile("s_waitcnt vmcnt(6)" ::: "memory");
    else if (VM == 0) asm volatile("s_waitcnt vmcnt(0)" ::: "memory");
    asm volatile("" ::: "memory");
    __builtin_amdgcn_s_barrier();
}

__global__ __launch_bounds__(512, 2) void gemm_i8(
    const unsigned char* __restrict__ A,
    const unsigned char* __restrict__ B,
    const float* __restrict__ sx,
    const float* __restrict__ sw,
    const float* __restrict__ bias,
    float* __restrict__ C)
{
    __shared__ __align__(16) unsigned char smem[147456];
    unsigned char* As0 = smem;               // stage 0: A 32KB + B 16KB
    unsigned char* Bs0 = smem + 32768;
    unsigned char* As1 = smem + 49152;       // stage 1
    unsigned char* Bs1 = smem + 81920;
    unsigned char* As2 = smem + 98304;       // stage 2
    unsigned char* Bs2 = smem + 131072;

    const int tid  = threadIdx.x;
    const int w    = tid >> 6;        // wave 0..7
    const int lane = tid & 63;
    const int l15  = lane & 15;
    const int quad = lane >> 4;
    const int m0   = blockIdx.y * 256;
    const int n0   = blockIdx.x * 128;
    const int wk   = w >> 2;          // k-half 0/1
    const int wm   = ((w >> 1) & 1) * 128;
    const int wn   = (w & 1) * 64;

    // staging assignment (verified R7): wave w / lane l covers row
    // (w*8 + l>>3) of each 64-row group, slot l&7 = global chunk (l&7)^(l>>3).
    const int r8 = lane >> 3;                        // 0..7
    const int sc = (lane & 7) ^ r8;                  // global k-chunk
    const unsigned char* gA = A + (size_t)(m0 + w * 8 + r8) * K_DIM + sc * 16;
    const unsigned char* gB = B + (size_t)(n0 + w * 8 + r8) * K_DIM + sc * 16;

    // frag reads: row = base + i*16 + l15 -> row&7 == l15&7. Wave's wanted
    // chunk = wk*4 + quad -> slot = chunk ^ (l15&7). Byte offset in row:
    const int fs = (((wk << 2) + quad) ^ (l15 & 7)) * 16;

    i32x4 acc[8][4] = {};

    // Prologue: stage tiles 0 (buf0) and 1 (buf1), A+B each.
    {
        async_load16(gA,                          As0 +         w * 1024);
        async_load16(gA + (size_t)64  * K_DIM,    As0 + 8192  + w * 1024);
        async_load16(gA + (size_t)128 * K_DIM,    As0 + 16384 + w * 1024);
        async_load16(gA + (size_t)192 * K_DIM,    As0 + 24576 + w * 1024);
        async_load16(gB,                          Bs0 +        w * 1024);
        async_load16(gB + (size_t)64 * K_DIM,     Bs0 + 8192 + w * 1024);
        async_load16(gA + 128,                        As1 +         w * 1024);
        async_load16(gA + 128 + (size_t)64  * K_DIM,  As1 + 8192  + w * 1024);
        async_load16(gA + 128 + (size_t)128 * K_DIM,  As1 + 16384 + w * 1024);
        async_load16(gA + 128 + (size_t)192 * K_DIM,  As1 + 24576 + w * 1024);
        async_load16(gB + 128,                        Bs1 +        w * 1024);
        async_load16(gB + 128 + (size_t)64 * K_DIM,   Bs1 + 8192 + w * 1024);
    }
    asm volatile("s_waitcnt vmcnt(6)" ::: "memory");   // tile 0 landed
    asm volatile("" ::: "memory");
    __builtin_amdgcn_s_barrier();

    // Main loop: tiles 0..29 (10 x unroll-3), each stages tile t+2.
    for (int it = 0; it < 10; ++it) {
        const int t = it * 3;
        ktile<true, 6>(As0, Bs0, As2, Bs2, (t + 2) * 128,
                       gA, gB, wm, wn, l15, fs, w, acc);
        ktile<true, 6>(As1, Bs1, As0, Bs0, (t + 3) * 128,
                       gA, gB, wm, wn, l15, fs, w, acc);
        ktile<true, 6>(As2, Bs2, As1, Bs1, (t + 4) * 128,
                       gA, gB, wm, wn, l15, fs, w, acc);
    }
    // Tiles 30, 31: no staging; drain for tile 31 at end of 30.
    ktile<false, 0>(As0, Bs0, As1, Bs1, 0, gA, gB, wm, wn, l15, fs, w, acc);
    ktile<false, -1>(As1, Bs1, As2, Bs2, 0, gA, gB, wm, wn, l15, fs, w, acc);
    // ktile's final barrier: all LDS reads retired -> smem reusable.

    // ---- k-pair reduction: wave w (wk=0) += wave w+4 (wk=1), via LDS ----
    i32x4* red = (i32x4*)smem;
    if (w == 4 || w == 5) {
        i32x4* dst = red + (w & 1) * 2048;
#pragma unroll
        for (int mi = 0; mi < 8; ++mi)
#pragma unroll
            for (int ni = 0; ni < 4; ++ni)
                dst[(mi * 4 + ni) * 64 + lane] = acc[mi][ni];
    }
    __syncthreads();
    if (w == 0 || w == 1) {
        const i32x4* src = red + (w & 1) * 2048;
#pragma unroll
        for (int mi = 0; mi < 8; ++mi)
#pragma unroll
            for (int ni = 0; ni < 4; ++ni) {
                const i32x4 v = src[(mi * 4 + ni) * 64 + lane];
                acc[mi][ni] = acc[mi][ni] + v;
            }
    }
    __syncthreads();
    if (w == 6 || w == 7) {
        i32x4* dst = red + (w & 1) * 2048;
#pragma unroll
        for (int mi = 0; mi < 8; ++mi)
#pragma unroll
            for (int ni = 0; ni < 4; ++ni)
                dst[(mi * 4 + ni) * 64 + lane] = acc[mi][ni];
    }
    __syncthreads();
    if (w == 2 || w == 3) {
        const i32x4* src = red + (w & 1) * 2048;
#pragma unroll
        for (int mi = 0; mi < 8; ++mi)
#pragma unroll
            for (int ni = 0; ni < 4; ++ni) {
                const i32x4 v = src[(mi * 4 + ni) * 64 + lane];
                acc[mi][ni] = acc[mi][ni] + v;
            }
    }

    // ---- epilogue (waves 0..3): C/D col = lane&15, row = quad*4+reg ----
    if (w < 4) {
        float swv[4], bv[4];
#pragma unroll
        for (int ni = 0; ni < 4; ++ni) {
            const int col = n0 + wn + ni * 16 + l15;
            swv[ni] = sw[col];
            bv[ni]  = bias[col];
        }
#pragma unroll
        for (int mi = 0; mi < 8; ++mi) {
            float sxr[4];
#pragma unroll
            for (int r = 0; r < 4; ++r)
                sxr[r] = sx[m0 + wm + mi * 16 + quad * 4 + r];
#pragma unroll
            for (int ni = 0; ni < 4; ++ni) {
                const int col = n0 + wn + ni * 16 + l15;
                float* cp = C + (size_t)(m0 + wm + mi * 16 + quad * 4) * N_DIM + col;
#pragma unroll
                for (int r = 0; r < 4; ++r)
                    cp[(size_t)r * N_DIM] =
                        (float)acc[mi][ni][r] * (sxr[r] * swv[ni]) + bv[ni];
            }
        }
    }
}

// ---------------- fallback (ws too small): naive fp32 ----------------
__global__ __launch_bounds__(256) void naive_kernel(
    const float* __restrict__ x, const float* __restrict__ cb,
    const int* __restrict__ codes, const float* __restrict__ bias,
    float* __restrict__ out)
{
    const size_t idx = (size_t)blockIdx.x * 256 + threadIdx.x;  // m*4096 + n
    const int n = (int)(idx & 4095);
    const int m = (int)(idx >> 12);
    const float* xr = x + (size_t)m * K_DIM;
    float s = bias[n];
    for (int g = 0; g < 32; ++g) {
        const float* cbr = cb + ((size_t)n * 32 + g) * 16;
        const int* cr = codes + ((size_t)n * 32 + g) * 128;
        const float* xg = xr + g * 128;
        for (int ss = 0; ss < 128; ++ss) s += xg[ss] * cbr[cr[ss]];
    }
    out[idx] = s;
}

extern "C" void kernel_launch(void* const* d_in, const int* in_sizes, int n_in,
                              void* d_out, int out_size, void* d_ws, size_t ws_size,
                              hipStream_t stream) {
    const float* x     = (const float*)d_in[0];   // [2,1024,4096] f32
    const float* cb    = (const float*)d_in[1];   // [4096,32,16]  f32
    const int*   codes = (const int*)d_in[2];     // [4096,32,128] i32
    const float* bias  = (const float*)d_in[3];   // [4096]        f32
    float* out = (float*)d_out;                   // [2,1024,4096] f32

    const size_t szW = (size_t)N_DIM * K_DIM;          // 16.78 MB i8
    const size_t szX = (size_t)M_DIM * K_DIM;          // 8.39 MB i8
    const size_t need = szW + szX + (N_DIM + M_DIM) * sizeof(float);

    if (ws_size >= need) {
        unsigned char* Wq = (unsigned char*)d_ws;
        unsigned char* Xq = Wq + szW;
        float* sw = (float*)(Xq + szX);
        float* sx = sw + N_DIM;
        prepass_q8<<<dim3(N_DIM + M_DIM), dim3(256), 0, stream>>>(
            cb, codes, x, (uint32_t*)Wq, (uint32_t*)Xq, sw, sx);
        gemm_i8<<<dim3(N_DIM / 128, M_DIM / 256), dim3(512), 0, stream>>>(
            Xq, Wq, sx, sw, bias, out);
    } else {
        naive_kernel<<<dim3((M_DIM * N_DIM) / 256), dim3(256), 0, stream>>>(x, cb, codes, bias, out);
    }
}